// Round 1
// baseline (407.506 us; speedup 1.0000x reference)
//
#include <hip/hip_runtime.h>
#include <math.h>

constexpr int kNpts   = 72;
constexpr int kPriors = 192;
constexpr int kLanes  = 4;
constexpr int kBatch  = 512;
constexpr int kStages = 3;
constexpr int kD      = 6 + kNpts;  // 78

__device__ __forceinline__ float smoothL1(float x) {
  float ax = fabsf(x);
  return ax < 1.0f ? 0.5f * x * x : ax - 0.5f;
}

__global__ void clr_init(const float* __restrict__ seg, float* __restrict__ out) {
  out[0] = seg[0];  // SEG_W = 1.0
}

__global__ __launch_bounds__(192) void clr_loss_kernel(
    const float* __restrict__ pred,   // (3,512,192,78)
    const float* __restrict__ tgt,    // (512,4,78)
    float* __restrict__ out) {
  const int blk = blockIdx.x;          // 0..1535  (stage*512 + b)
  const int b   = blk & (kBatch - 1);
  const int tid = threadIdx.x;         // 0..191, one prior per thread

  __shared__ float s_tgt[kLanes][kD];
  __shared__ float s_iou[kLanes][kPriors];
  __shared__ float s_cost[kLanes][kPriors];
  __shared__ int   s_dynk[kLanes];
  __shared__ float s_sc[3][4];         // 3 waves x up to 4 reduced values

  // ---- stage targets into LDS ----
  const float* tg = tgt + (size_t)b * kLanes * kD;
  for (int t = tid; t < kLanes * kD; t += 192) (&s_tgt[0][0])[t] = tg[t];
  __syncthreads();

  bool validL[kLanes];
  int num_t = 0;
#pragma unroll
  for (int j = 0; j < kLanes; ++j) {
    validL[j] = (s_tgt[j][1] == 1.0f);
    num_t += validL[j] ? 1 : 0;
  }
  const bool has_t = num_t > 0;

  // ---- load my prior row header ----
  const float* pr = pred + ((size_t)blk * kPriors + tid) * kD;
  const float p0 = pr[0], p1 = pr[1], p2 = pr[2], p3 = pr[3], p4 = pr[4], p5 = pr[5];

  // ---- streaming pass over 72 points: iou ovr/union, dist, t_len ----
  float ovr[kLanes]  = {0, 0, 0, 0};
  float uni[kLanes]  = {0, 0, 0, 0};
  float dsum[kLanes] = {0, 0, 0, 0};
  float tlen[kLanes] = {0, 0, 0, 0};
  for (int k = 0; k < kNpts; ++k) {
    float px  = pr[6 + k] * 799.0f;   // * (IMG_W - 1)
    float px1 = px - 15.0f, px2 = px + 15.0f;
#pragma unroll
    for (int j = 0; j < kLanes; ++j) {
      float tx = s_tgt[j][6 + k];
      if (tx >= 0.0f && tx < 800.0f) {   // !invalid (uniform across wave)
        float tx1 = tx - 15.0f, tx2 = tx + 15.0f;
        ovr[j]  += fminf(px2, tx2) - fmaxf(px1, tx1);
        uni[j]  += fmaxf(px2, tx2) - fminf(px1, tx1);
        dsum[j] += fabsf(tx - px);
        tlen[j] += 1.0f;
      }
    }
  }

  float iou[kLanes], dist[kLanes], sd[kLanes], th[kLanes];
  float md = -INFINITY, ms = -INFINITY, mt = -INFINITY;
  const float py = p2 * 319.0f, pxc = p3 * 799.0f;
#pragma unroll
  for (int j = 0; j < kLanes; ++j) {
    iou[j]  = ovr[j] / (uni[j] + 1e-9f);
    dist[j] = dsum[j] / (tlen[j] + 1e-9f);
    float dy = py - s_tgt[j][2] * 319.0f;
    float dx = pxc - s_tgt[j][3];
    sd[j] = sqrtf(dy * dy + dx * dx);
    th[j] = fabsf(p4 - s_tgt[j][4]) * 180.0f;
    if (validL[j]) {
      md = fmaxf(md, dist[j]);
      ms = fmaxf(ms, sd[j]);
      mt = fmaxf(mt, th[j]);
    }
  }

  // ---- block max reduce (3 values) for norm_score denominators ----
#pragma unroll
  for (int off = 32; off; off >>= 1) {
    md = fmaxf(md, __shfl_down(md, off, 64));
    ms = fmaxf(ms, __shfl_down(ms, off, 64));
    mt = fmaxf(mt, __shfl_down(mt, off, 64));
  }
  if ((tid & 63) == 0) {
    int w = tid >> 6;
    s_sc[w][0] = md; s_sc[w][1] = ms; s_sc[w][2] = mt;
  }
  __syncthreads();
  md = fmaxf(fmaxf(s_sc[0][0], s_sc[1][0]), s_sc[2][0]);
  ms = fmaxf(fmaxf(s_sc[0][1], s_sc[1][1]), s_sc[2][1]);
  mt = fmaxf(fmaxf(s_sc[0][2], s_sc[1][2]), s_sc[2][2]);
  if (!has_t) { md = 1.0f; ms = 1.0f; mt = 1.0f; }

  // ---- cls_cost (class-1 focal-style cost) ----
  const float sp1  = 1.0f / (1.0f + expf(-p1));
  const float neg1 = -logf(1.0f - sp1 + 1e-12f) * 0.75f * sp1 * sp1;
  const float om1  = 1.0f - sp1;
  const float pos1 = -logf(sp1 + 1e-12f) * 0.25f * om1 * om1;
  const float cls_cost = pos1 - neg1;

  // ---- cost matrix + iou_sg into LDS ----
  float costr[kLanes];
#pragma unroll
  for (int j = 0; j < kLanes; ++j) {
    s_iou[j][tid] = validL[j] ? fmaxf(iou[j], 0.0f) : 0.0f;
    float c;
    if (validL[j]) {
      float a = (1.0f - dist[j] / md) + 0.01f;
      float s = (1.0f - sd[j] / ms) + 0.01f;
      float t = (1.0f - th[j] / mt) + 0.01f;
      float g = a * s * t;
      c = cls_cost - g * g * 3.0f;   // -(a*s*t)^2*3 + cls_cost
    } else {
      c = INFINITY;
    }
    costr[j] = c;
    s_cost[j][tid] = c;
  }
  __syncthreads();

  // ---- dyn_k: top-4 iou sum per lane (serial scan, descending-order sum) ----
  if (tid < kLanes) {
    float t0 = -1.0f, t1 = -1.0f, t2 = -1.0f, t3 = -1.0f;
    for (int i = 0; i < kPriors; ++i) {
      float v = s_iou[tid][i];
      if (v > t0)      { t3 = t2; t2 = t1; t1 = t0; t0 = v; }
      else if (v > t1) { t3 = t2; t2 = t1; t1 = v; }
      else if (v > t2) { t3 = t2; t2 = v; }
      else if (v > t3) { t3 = v; }
    }
    float s = t0 + t1 + t2 + t3;
    int k = (int)s;                   // trunc toward zero (s >= 0)
    s_dynk[tid] = k > 1 ? k : 1;
  }
  __syncthreads();

  // ---- stable ranks via counting (LDS broadcast scans) ----
  int Mi[kLanes];
  int msum = 0;
#pragma unroll
  for (int j = 0; j < kLanes; ++j) {
    float myc = costr[j];
    int cnt = 0;
    for (int i = 0; i < kPriors; ++i) {
      float c = s_cost[j][i];
      cnt += (c < myc || (c == myc && i < tid)) ? 1 : 0;
    }
    Mi[j] = (validL[j] && cnt < s_dynk[j]) ? 1 : 0;
    msum += Mi[j];
  }

  // argmin over lanes (first-min semantics)
  float amin = costr[0];
  int aidx = 0;
#pragma unroll
  for (int j = 1; j < kLanes; ++j)
    if (costr[j] < amin) { amin = costr[j]; aidx = j; }

  float Mf[kLanes];
#pragma unroll
  for (int j = 0; j < kLanes; ++j) Mf[j] = (float)Mi[j];
  if (msum > 1) {        // multi: zero col 0, then set argmin col to 1 (in order)
    Mf[0] = 0.0f;
    Mf[aidx] = 1.0f;
  }

  const float mfsum = Mf[0] + Mf[1] + Mf[2] + Mf[3];
  const int cls_t = (mfsum > 0.0f) ? 1 : 0;

  // ---- focal classification term (softmax over 2 logits) ----
  const float mx = fmaxf(p0, p1);
  const float e0 = expf(p0 - mx), e1 = expf(p1 - mx);
  const float inv = 1.0f / (e0 + e1);
  const float q = (cls_t ? e1 : e0) * inv + 1e-8f;
  const float omq = 1.0f - q;
  const float focal = -0.25f * omq * omq * logf(q);

  // ---- reg (smooth L1) + iou terms for matched pairs ----
  const float pred_start = fminf(fmaxf(rintf(p2 * 71.0f), 0.0f), 71.0f);
  const float py0 = p2 * 71.0f, py1 = p3 * 799.0f, py2t = p4 * 180.0f, py3 = p5 * 71.0f;
  float regc = 0.0f, iouc = 0.0f;
#pragma unroll
  for (int j = 0; j < kLanes; ++j) {
    if (Mf[j] > 0.0f) {
      float t30 = s_tgt[j][2] * 71.0f;
      float t31 = s_tgt[j][3];
      float t32 = s_tgt[j][4] * 180.0f;
      float tstart = rintf(s_tgt[j][2] * 71.0f);
      float tlp = s_tgt[j][5] - (pred_start - tstart);
      float sl = smoothL1(py0 - t30) + smoothL1(py1 - t31) + smoothL1(py2t - t32)
               + smoothL1(py3 - tlp);
      regc += sl;
      iouc += 1.0f - iou[j];
    }
  }

  // ---- block sum reduce (4 values) ----
  float v0 = mfsum, v1 = focal, v2 = regc, v3 = iouc;
#pragma unroll
  for (int off = 32; off; off >>= 1) {
    v0 += __shfl_down(v0, off, 64);
    v1 += __shfl_down(v1, off, 64);
    v2 += __shfl_down(v2, off, 64);
    v3 += __shfl_down(v3, off, 64);
  }
  __syncthreads();   // s_sc reuse barrier (cheap; keeps scratch hazard-free)
  if ((tid & 63) == 0) {
    int w = tid >> 6;
    s_sc[w][0] = v0; s_sc[w][1] = v1; s_sc[w][2] = v2; s_sc[w][3] = v3;
  }
  __syncthreads();

  if (tid == 0) {
    float nm      = s_sc[0][0] + s_sc[1][0] + s_sc[2][0];
    float cls_sum = s_sc[0][1] + s_sc[1][1] + s_sc[2][1];
    float reg_sum = s_sc[0][2] + s_sc[1][2] + s_sc[2][2];
    float iou_sum = s_sc[0][3] + s_sc[1][3] + s_sc[2][3];

    float cls_term = cls_sum / (has_t ? (float)num_t : 1.0f);
    float reg_term = has_t ? reg_sum / fmaxf(nm * 4.0f, 1.0f) : 0.0f;
    float iou_term = has_t ? iou_sum / fmaxf(nm, 1.0f) : 0.0f;

    float sample = 2.0f * cls_term + 0.2f * reg_term + 2.0f * iou_term;
    atomicAdd(out, sample * (1.0f / (float)(kBatch * kStages)));
  }
}

extern "C" void kernel_launch(void* const* d_in, const int* in_sizes, int n_in,
                              void* d_out, int out_size, void* d_ws, size_t ws_size,
                              hipStream_t stream) {
  const float* pred = (const float*)d_in[0];   // (3,512,192,78) f32
  const float* tgt  = (const float*)d_in[1];   // (512,4,78) f32
  const float* seg  = (const float*)d_in[2];   // scalar f32
  float* out = (float*)d_out;                  // scalar f32

  clr_init<<<1, 1, 0, stream>>>(seg, out);
  clr_loss_kernel<<<kStages * kBatch, 192, 0, stream>>>(pred, tgt, out);
}

// Round 2
// 164.019 us; speedup vs baseline: 2.4845x; 2.4845x over previous
//
#include <hip/hip_runtime.h>
#include <math.h>

constexpr int kNpts   = 72;
constexpr int kPriors = 192;
constexpr int kLanes  = 4;
constexpr int kBatch  = 512;
constexpr int kStages = 3;
constexpr int kD      = 6 + kNpts;  // 78

typedef unsigned long long u64;

__device__ __forceinline__ float smoothL1(float x) {
  float ax = fabsf(x);
  return ax < 1.0f ? 0.5f * x * x : ax - 0.5f;
}

// monotone map float -> uint32 (ascending order preserved, handles +/-inf)
__device__ __forceinline__ unsigned ordF(float f) {
  unsigned b = __float_as_uint(f);
  return (b & 0x80000000u) ? ~b : (b | 0x80000000u);
}

__device__ __forceinline__ void cswapA(u64& a, u64& b) {        // ascending
  if (b < a) { u64 t = a; a = b; b = t; }
}
__device__ __forceinline__ void cswapD(float& a, float& b) {    // descending
  if (b > a) { float t = a; a = b; b = t; }
}

__global__ void clr_init(const float* __restrict__ seg, float* __restrict__ out) {
  out[0] = seg[0];  // SEG_W = 1.0
}

// streaming-pass element update (px pre-scaled by 799)
#define PROC(TX, PX)                                                   \
  {                                                                    \
    float tx = (TX);                                                   \
    if (tx >= 0.0f && tx < 800.0f) {                                   \
      float pxv = (PX);                                                \
      float px1 = pxv - 15.0f, px2 = pxv + 15.0f;                      \
      float tx1 = tx - 15.0f, tx2 = tx + 15.0f;                        \
      ovr  += fminf(px2, tx2) - fmaxf(px1, tx1);                       \
      uni  += fmaxf(px2, tx2) - fminf(px1, tx1);                       \
      dsum += fabsf(tx - pxv);                                         \
      tlen += 1.0f;                                                    \
    }                                                                  \
  }

__global__ __launch_bounds__(192) void clr_loss_kernel(
    const float* __restrict__ pred,   // (3,512,192,78)
    const float* __restrict__ tgt,    // (512,4,78)
    float* __restrict__ out) {
  const int blk  = blockIdx.x;          // stage*512 + b
  const int b    = blk & (kBatch - 1);
  const int tid  = threadIdx.x;         // one prior per thread
  const int wav  = tid >> 6;
  const int lane = tid & 63;

  __shared__ float s_txs[kLanes][kNpts];    // 16B-aligned rows (288 B)
  __shared__ float s_hdr[kLanes][6];
  __shared__ float s_cost[kLanes][kPriors];
  __shared__ float s_iou[kLanes][kPriors];
  __shared__ u64   s_thr[kLanes];           // cost key of rank (dyn_k-1)
  __shared__ float s_sc[3][4];

  // ---- stage targets into LDS (rearranged: xs 16B-aligned) ----
  const float* tg = tgt + (size_t)b * kLanes * kD;
  for (int t = tid; t < kLanes * kD; t += 192) {
    int j = t / kD, c = t - j * kD;
    float v = tg[t];
    if (c < 6) s_hdr[j][c] = v; else s_txs[j][c - 6] = v;
  }

  // ---- burst-load my prior row into registers (39 x float2, 8B aligned) ----
  const float*  pr   = pred + ((size_t)blk * kPriors + tid) * kD;
  const float2* rowv = (const float2*)pr;
  float2 h0 = rowv[0], h1 = rowv[1], h2 = rowv[2];
  float px[kNpts];
#pragma unroll
  for (int q = 0; q < 36; ++q) {
    float2 v = rowv[3 + q];
    px[2 * q]     = v.x * 799.0f;
    px[2 * q + 1] = v.y * 799.0f;
  }
  const float p0 = h0.x, p1 = h0.y, p2 = h1.x, p3 = h1.y, p4 = h2.x, p5 = h2.y;

  __syncthreads();

  bool validL[kLanes];
  int num_t = 0;
#pragma unroll
  for (int j = 0; j < kLanes; ++j) {
    validL[j] = (s_hdr[j][1] == 1.0f);
    num_t += validL[j] ? 1 : 0;
  }
  const bool has_t = num_t > 0;

  // ---- streaming pass (j-outer, float4 broadcast reads of target xs) ----
  float iou[kLanes], dist[kLanes], sd[kLanes], th[kLanes];
  float md = -INFINITY, ms = -INFINITY, mt = -INFINITY;
  const float py = p2 * 319.0f, pxc = p3 * 799.0f;
#pragma unroll
  for (int j = 0; j < kLanes; ++j) {
    float ovr = 0.0f, uni = 0.0f, dsum = 0.0f, tlen = 0.0f;
    if (validL[j]) {
      const float4* tv = (const float4*)&s_txs[j][0];
#pragma unroll
      for (int q = 0; q < 18; ++q) {
        float4 t4 = tv[q];
        PROC(t4.x, px[4 * q + 0]);
        PROC(t4.y, px[4 * q + 1]);
        PROC(t4.z, px[4 * q + 2]);
        PROC(t4.w, px[4 * q + 3]);
      }
    }
    iou[j]  = ovr / (uni + 1e-9f);
    dist[j] = dsum / (tlen + 1e-9f);
    float dy = py - s_hdr[j][2] * 319.0f;
    float dx = pxc - s_hdr[j][3];
    sd[j] = sqrtf(dy * dy + dx * dx);
    th[j] = fabsf(p4 - s_hdr[j][4]) * 180.0f;
    if (validL[j]) {
      md = fmaxf(md, dist[j]);
      ms = fmaxf(ms, sd[j]);
      mt = fmaxf(mt, th[j]);
    }
  }

  // ---- block max reduce for norm_score denominators ----
#pragma unroll
  for (int off = 32; off; off >>= 1) {
    md = fmaxf(md, __shfl_down(md, off, 64));
    ms = fmaxf(ms, __shfl_down(ms, off, 64));
    mt = fmaxf(mt, __shfl_down(mt, off, 64));
  }
  if (lane == 0) { s_sc[wav][0] = md; s_sc[wav][1] = ms; s_sc[wav][2] = mt; }
  __syncthreads();
  md = fmaxf(fmaxf(s_sc[0][0], s_sc[1][0]), s_sc[2][0]);
  ms = fmaxf(fmaxf(s_sc[0][1], s_sc[1][1]), s_sc[2][1]);
  mt = fmaxf(fmaxf(s_sc[0][2], s_sc[1][2]), s_sc[2][2]);
  if (!has_t) { md = 1.0f; ms = 1.0f; mt = 1.0f; }

  // ---- cls_cost ----
  const float sp1  = 1.0f / (1.0f + expf(-p1));
  const float neg1 = -logf(1.0f - sp1 + 1e-12f) * 0.75f * sp1 * sp1;
  const float om1  = 1.0f - sp1;
  const float pos1 = -logf(sp1 + 1e-12f) * 0.25f * om1 * om1;
  const float cls_cost = pos1 - neg1;

  // ---- cost matrix + iou_sg into LDS ----
  float costr[kLanes];
#pragma unroll
  for (int j = 0; j < kLanes; ++j) {
    s_iou[j][tid] = validL[j] ? fmaxf(iou[j], 0.0f) : 0.0f;
    float c;
    if (validL[j]) {
      float a = (1.0f - dist[j] / md) + 0.01f;
      float s = (1.0f - sd[j] / ms) + 0.01f;
      float t = (1.0f - th[j] / mt) + 0.01f;
      float g = a * s * t;
      c = cls_cost - g * g * 3.0f;
    } else {
      c = INFINITY;
    }
    costr[j] = c;
    s_cost[j][tid] = c;
  }
  __syncthreads();

  // ---- per-lane top-4: cost (4-smallest keys) + iou (4-largest) ----
  // one wave owns lane-column j (wave 0 also takes j=3); wave-wide butterfly
  for (int j = wav; j < kLanes; j += 3) {
    u64 k0, k1, k2, k3;
    {
      float c0 = s_cost[j][lane], c1 = s_cost[j][lane + 64], c2 = s_cost[j][lane + 128];
      k0 = ((u64)ordF(c0) << 32) | (unsigned)lane;
      k1 = ((u64)ordF(c1) << 32) | (unsigned)(lane + 64);
      k2 = ((u64)ordF(c2) << 32) | (unsigned)(lane + 128);
      k3 = 0xFFFFFFFFFFFFFFFFull;
      cswapA(k0, k1); cswapA(k0, k2); cswapA(k1, k2);
#pragma unroll
      for (int off = 1; off < 64; off <<= 1) {
        u64 b0 = __shfl_xor(k0, off), b1 = __shfl_xor(k1, off);
        u64 b2 = __shfl_xor(k2, off), b3 = __shfl_xor(k3, off);
        u64 m0 = k0 < b3 ? k0 : b3, m1 = k1 < b2 ? k1 : b2;
        u64 m2 = k2 < b1 ? k2 : b1, m3 = k3 < b0 ? k3 : b0;
        cswapA(m0, m2); cswapA(m1, m3); cswapA(m0, m1); cswapA(m2, m3);
        k0 = m0; k1 = m1; k2 = m2; k3 = m3;
      }
    }
    float t0, t1, t2, t3;
    {
      t0 = s_iou[j][lane]; t1 = s_iou[j][lane + 64]; t2 = s_iou[j][lane + 128];
      t3 = -1.0f;
      cswapD(t0, t1); cswapD(t0, t2); cswapD(t1, t2);
#pragma unroll
      for (int off = 1; off < 64; off <<= 1) {
        float b0 = __shfl_xor(t0, off), b1 = __shfl_xor(t1, off);
        float b2 = __shfl_xor(t2, off), b3 = __shfl_xor(t3, off);
        float m0 = fmaxf(t0, b3), m1 = fmaxf(t1, b2);
        float m2 = fmaxf(t2, b1), m3 = fmaxf(t3, b0);
        cswapD(m0, m2); cswapD(m1, m3); cswapD(m0, m1); cswapD(m2, m3);
        t0 = m0; t1 = m1; t2 = m2; t3 = m3;
      }
    }
    if (lane == 0) {
      float s = ((t0 + t1) + t2) + t3;       // descending order, matches top_k sum
      int dk = (int)s;                       // iou < 1 strictly => dk <= 3
      if (dk < 1) dk = 1;
      if (dk > 4) dk = 4;
      s_thr[j] = dk == 1 ? k0 : dk == 2 ? k1 : dk == 3 ? k2 : k3;
    }
  }
  __syncthreads();

  // ---- membership: my stable-rank < dyn_k  <=>  my key <= kth-smallest key ----
  int Mi[kLanes];
  int msum = 0;
#pragma unroll
  for (int j = 0; j < kLanes; ++j) {
    u64 myk = ((u64)ordF(costr[j]) << 32) | (unsigned)tid;
    Mi[j] = (validL[j] && myk <= s_thr[j]) ? 1 : 0;
    msum += Mi[j];
  }

  // argmin over lanes (first-min semantics)
  float amin = costr[0];
  int aidx = 0;
#pragma unroll
  for (int j = 1; j < kLanes; ++j)
    if (costr[j] < amin) { amin = costr[j]; aidx = j; }

  float Mf[kLanes];
#pragma unroll
  for (int j = 0; j < kLanes; ++j) Mf[j] = (float)Mi[j];
  if (msum > 1) {
    Mf[0] = 0.0f;
    Mf[aidx] = 1.0f;
  }

  const float mfsum = Mf[0] + Mf[1] + Mf[2] + Mf[3];
  const int cls_t = (mfsum > 0.0f) ? 1 : 0;

  // ---- focal classification term ----
  const float mx = fmaxf(p0, p1);
  const float e0 = expf(p0 - mx), e1 = expf(p1 - mx);
  const float inv = 1.0f / (e0 + e1);
  const float q = (cls_t ? e1 : e0) * inv + 1e-8f;
  const float omq = 1.0f - q;
  const float focal = -0.25f * omq * omq * logf(q);

  // ---- reg (smooth L1) + iou terms for matched pairs ----
  const float pred_start = fminf(fmaxf(rintf(p2 * 71.0f), 0.0f), 71.0f);
  const float py0 = p2 * 71.0f, py1 = p3 * 799.0f, py2t = p4 * 180.0f, py3 = p5 * 71.0f;
  float regc = 0.0f, iouc = 0.0f;
#pragma unroll
  for (int j = 0; j < kLanes; ++j) {
    if (Mf[j] > 0.0f) {
      float t30 = s_hdr[j][2] * 71.0f;
      float t31 = s_hdr[j][3];
      float t32 = s_hdr[j][4] * 180.0f;
      float tstart = rintf(s_hdr[j][2] * 71.0f);
      float tlp = s_hdr[j][5] - (pred_start - tstart);
      regc += smoothL1(py0 - t30) + smoothL1(py1 - t31) + smoothL1(py2t - t32)
            + smoothL1(py3 - tlp);
      iouc += 1.0f - iou[j];
    }
  }

  // ---- block sum reduce (4 values) ----
  float v0 = mfsum, v1 = focal, v2 = regc, v3 = iouc;
#pragma unroll
  for (int off = 32; off; off >>= 1) {
    v0 += __shfl_down(v0, off, 64);
    v1 += __shfl_down(v1, off, 64);
    v2 += __shfl_down(v2, off, 64);
    v3 += __shfl_down(v3, off, 64);
  }
  __syncthreads();   // s_sc reuse hazard
  if (lane == 0) {
    s_sc[wav][0] = v0; s_sc[wav][1] = v1; s_sc[wav][2] = v2; s_sc[wav][3] = v3;
  }
  __syncthreads();

  if (tid == 0) {
    float nm      = s_sc[0][0] + s_sc[1][0] + s_sc[2][0];
    float cls_sum = s_sc[0][1] + s_sc[1][1] + s_sc[2][1];
    float reg_sum = s_sc[0][2] + s_sc[1][2] + s_sc[2][2];
    float iou_sum = s_sc[0][3] + s_sc[1][3] + s_sc[2][3];

    float cls_term = cls_sum / (has_t ? (float)num_t : 1.0f);
    float reg_term = has_t ? reg_sum / fmaxf(nm * 4.0f, 1.0f) : 0.0f;
    float iou_term = has_t ? iou_sum / fmaxf(nm, 1.0f) : 0.0f;

    float sample = 2.0f * cls_term + 0.2f * reg_term + 2.0f * iou_term;
    atomicAdd(out, sample * (1.0f / (float)(kBatch * kStages)));
  }
}

extern "C" void kernel_launch(void* const* d_in, const int* in_sizes, int n_in,
                              void* d_out, int out_size, void* d_ws, size_t ws_size,
                              hipStream_t stream) {
  const float* pred = (const float*)d_in[0];   // (3,512,192,78) f32
  const float* tgt  = (const float*)d_in[1];   // (512,4,78) f32
  const float* seg  = (const float*)d_in[2];   // scalar f32
  float* out = (float*)d_out;                  // scalar f32

  clr_init<<<1, 1, 0, stream>>>(seg, out);
  clr_loss_kernel<<<kStages * kBatch, 192, 0, stream>>>(pred, tgt, out);
}

// Round 3
// 148.733 us; speedup vs baseline: 2.7398x; 1.1028x over previous
//
#include <hip/hip_runtime.h>
#include <math.h>

constexpr int kNpts   = 72;
constexpr int kPriors = 192;
constexpr int kLanes  = 4;
constexpr int kBatch  = 512;
constexpr int kStages = 3;
constexpr int kD      = 6 + kNpts;  // 78

typedef unsigned long long u64;

__device__ __forceinline__ float smoothL1(float x) {
  float ax = fabsf(x);
  return ax < 1.0f ? 0.5f * x * x : ax - 0.5f;
}

// monotone map float -> uint32 (ascending order preserved, handles +/-inf)
__device__ __forceinline__ unsigned ordF(float f) {
  unsigned b = __float_as_uint(f);
  return (b & 0x80000000u) ? ~b : (b | 0x80000000u);
}

__device__ __forceinline__ void cswapA(u64& a, u64& b) {        // ascending
  if (b < a) { u64 t = a; a = b; b = t; }
}
__device__ __forceinline__ void cswapD(float& a, float& b) {    // descending
  if (b > a) { float t = a; a = b; b = t; }
}

__global__ void clr_init(const float* __restrict__ seg, float* __restrict__ out) {
  out[0] = seg[0];  // SEG_W = 1.0
}

__global__ __launch_bounds__(192) void clr_loss_kernel(
    const float* __restrict__ pred,   // (3,512,192,78)
    const float* __restrict__ tgt,    // (512,4,78)
    float* __restrict__ out) {
  const int blk  = blockIdx.x;          // stage*512 + b
  const int b    = blk & (kBatch - 1);
  const int tid  = threadIdx.x;         // one prior per thread
  const int wav  = tid >> 6;
  const int lane = tid & 63;

  __shared__ float s_tx[kNpts][kLanes];   // transposed: point-major, float4 rows
  __shared__ float s_m [kNpts][kLanes];   // 0/1 validity mask, same layout
  __shared__ float s_hdr[kLanes][6];
  __shared__ float s_cost[kLanes][kPriors];
  __shared__ float s_iou[kLanes][kPriors];
  __shared__ u64   s_thr[kLanes];         // cost key of rank (dyn_k-1)
  __shared__ float s_sc[3][4];

  // ---- stage targets into LDS (transposed xs + mask precompute) ----
  const float* tg = tgt + (size_t)b * kLanes * kD;
  for (int t = tid; t < kLanes * kNpts; t += 192) {
    int j = t / kNpts, k = t - j * kNpts;
    float v = tg[j * kD + 6 + k];
    s_tx[k][j] = v;
    s_m [k][j] = (v >= 0.0f && v < 800.0f) ? 1.0f : 0.0f;
  }
  if (tid < kLanes * 6) {
    int j = tid / 6, c = tid - j * 6;
    s_hdr[j][c] = tg[j * kD + c];
  }

  // ---- burst-load my prior row (39 x float2, 8B aligned) ----
  const float*  pr   = pred + ((size_t)blk * kPriors + tid) * kD;
  const float2* rowv = (const float2*)pr;
  float2 h0 = rowv[0], h1 = rowv[1], h2 = rowv[2];
  float px[kNpts];
#pragma unroll
  for (int q = 0; q < 36; ++q) {
    float2 v = rowv[3 + q];
    px[2 * q]     = v.x * 799.0f;
    px[2 * q + 1] = v.y * 799.0f;
  }
  const float p0 = h0.x, p1 = h0.y, p2 = h1.x, p3 = h1.y, p4 = h2.x, p5 = h2.y;

  __syncthreads();

  bool validL[kLanes];
  int num_t = 0;
#pragma unroll
  for (int j = 0; j < kLanes; ++j) {
    validL[j] = (s_hdr[j][1] == 1.0f);
    num_t += validL[j] ? 1 : 0;
  }
  const bool has_t = num_t > 0;

  // ---- collapsed streaming pass: only dsum needed (2 VALU/elem) ----
  float ds[kLanes] = {0.0f, 0.0f, 0.0f, 0.0f};
  {
    const float4* tx4 = (const float4*)&s_tx[0][0];
    const float4* m4  = (const float4*)&s_m[0][0];
#pragma unroll
    for (int k = 0; k < kNpts; ++k) {
      float4 t = tx4[k];
      float4 m = m4[k];
      float p = px[k];
      ds[0] = fmaf(m.x, fabsf(t.x - p), ds[0]);
      ds[1] = fmaf(m.y, fabsf(t.y - p), ds[1]);
      ds[2] = fmaf(m.z, fabsf(t.z - p), ds[2]);
      ds[3] = fmaf(m.w, fabsf(t.w - p), ds[3]);
    }
  }

  // ---- per-lane scalars: iou/dist from closed form; sd, th ----
  float iou[kLanes], dist[kLanes], sd[kLanes], th[kLanes];
  float md = -INFINITY, ms = -INFINITY, mt = -INFINITY;
  const float py = p2 * 319.0f, pxc = p3 * 799.0f;
#pragma unroll
  for (int j = 0; j < kLanes; ++j) {
    float tlen = validL[j] ? s_hdr[j][5] : 0.0f;   // = valid point count
    float ovr = fmaf(tlen, 30.0f, -ds[j]);
    float uni = fmaf(tlen, 30.0f,  ds[j]) + 1e-9f;
    iou[j]  = ovr / uni;
    dist[j] = ds[j] / (tlen + 1e-9f);
    float dy = py - s_hdr[j][2] * 319.0f;
    float dx = pxc - s_hdr[j][3];
    sd[j] = sqrtf(dy * dy + dx * dx);
    th[j] = fabsf(p4 - s_hdr[j][4]) * 180.0f;
    if (validL[j]) {
      md = fmaxf(md, dist[j]);
      ms = fmaxf(ms, sd[j]);
      mt = fmaxf(mt, th[j]);
    }
  }

  // ---- block max reduce for norm_score denominators ----
#pragma unroll
  for (int off = 32; off; off >>= 1) {
    md = fmaxf(md, __shfl_down(md, off, 64));
    ms = fmaxf(ms, __shfl_down(ms, off, 64));
    mt = fmaxf(mt, __shfl_down(mt, off, 64));
  }
  if (lane == 0) { s_sc[wav][0] = md; s_sc[wav][1] = ms; s_sc[wav][2] = mt; }
  __syncthreads();
  md = fmaxf(fmaxf(s_sc[0][0], s_sc[1][0]), s_sc[2][0]);
  ms = fmaxf(fmaxf(s_sc[0][1], s_sc[1][1]), s_sc[2][1]);
  mt = fmaxf(fmaxf(s_sc[0][2], s_sc[1][2]), s_sc[2][2]);
  if (!has_t) { md = 1.0f; ms = 1.0f; mt = 1.0f; }

  // ---- cls_cost ----
  const float sp1  = 1.0f / (1.0f + expf(-p1));
  const float neg1 = -logf(1.0f - sp1 + 1e-12f) * 0.75f * sp1 * sp1;
  const float om1  = 1.0f - sp1;
  const float pos1 = -logf(sp1 + 1e-12f) * 0.25f * om1 * om1;
  const float cls_cost = pos1 - neg1;

  // ---- cost matrix + iou_sg into LDS ----
  float costr[kLanes];
#pragma unroll
  for (int j = 0; j < kLanes; ++j) {
    s_iou[j][tid] = validL[j] ? fmaxf(iou[j], 0.0f) : 0.0f;
    float c;
    if (validL[j]) {
      float a = (1.0f - dist[j] / md) + 0.01f;
      float s = (1.0f - sd[j] / ms) + 0.01f;
      float t = (1.0f - th[j] / mt) + 0.01f;
      float g = a * s * t;
      c = cls_cost - g * g * 3.0f;
    } else {
      c = INFINITY;
    }
    costr[j] = c;
    s_cost[j][tid] = c;
  }
  __syncthreads();

  // ---- per-lane top-4: cost (4-smallest keys) + iou (4-largest) ----
  for (int j = wav; j < kLanes; j += 3) {
    u64 k0, k1, k2, k3;
    {
      float c0 = s_cost[j][lane], c1 = s_cost[j][lane + 64], c2 = s_cost[j][lane + 128];
      k0 = ((u64)ordF(c0) << 32) | (unsigned)lane;
      k1 = ((u64)ordF(c1) << 32) | (unsigned)(lane + 64);
      k2 = ((u64)ordF(c2) << 32) | (unsigned)(lane + 128);
      k3 = 0xFFFFFFFFFFFFFFFFull;
      cswapA(k0, k1); cswapA(k0, k2); cswapA(k1, k2);
#pragma unroll
      for (int off = 1; off < 64; off <<= 1) {
        u64 b0 = __shfl_xor(k0, off), b1 = __shfl_xor(k1, off);
        u64 b2 = __shfl_xor(k2, off), b3 = __shfl_xor(k3, off);
        u64 m0 = k0 < b3 ? k0 : b3, m1 = k1 < b2 ? k1 : b2;
        u64 m2 = k2 < b1 ? k2 : b1, m3 = k3 < b0 ? k3 : b0;
        cswapA(m0, m2); cswapA(m1, m3); cswapA(m0, m1); cswapA(m2, m3);
        k0 = m0; k1 = m1; k2 = m2; k3 = m3;
      }
    }
    float t0, t1, t2, t3;
    {
      t0 = s_iou[j][lane]; t1 = s_iou[j][lane + 64]; t2 = s_iou[j][lane + 128];
      t3 = -1.0f;
      cswapD(t0, t1); cswapD(t0, t2); cswapD(t1, t2);
#pragma unroll
      for (int off = 1; off < 64; off <<= 1) {
        float b0 = __shfl_xor(t0, off), b1 = __shfl_xor(t1, off);
        float b2 = __shfl_xor(t2, off), b3 = __shfl_xor(t3, off);
        float m0 = fmaxf(t0, b3), m1 = fmaxf(t1, b2);
        float m2 = fmaxf(t2, b1), m3 = fmaxf(t3, b0);
        cswapD(m0, m2); cswapD(m1, m3); cswapD(m0, m1); cswapD(m2, m3);
        t0 = m0; t1 = m1; t2 = m2; t3 = m3;
      }
    }
    if (lane == 0) {
      float s = ((t0 + t1) + t2) + t3;       // descending order, matches top_k sum
      int dk = (int)s;
      if (dk < 1) dk = 1;
      if (dk > 4) dk = 4;
      s_thr[j] = dk == 1 ? k0 : dk == 2 ? k1 : dk == 3 ? k2 : k3;
    }
  }
  __syncthreads();

  // ---- membership: stable-rank < dyn_k  <=>  key <= kth-smallest key ----
  int Mi[kLanes];
  int msum = 0;
#pragma unroll
  for (int j = 0; j < kLanes; ++j) {
    u64 myk = ((u64)ordF(costr[j]) << 32) | (unsigned)tid;
    Mi[j] = (validL[j] && myk <= s_thr[j]) ? 1 : 0;
    msum += Mi[j];
  }

  // argmin over lanes (first-min semantics)
  float amin = costr[0];
  int aidx = 0;
#pragma unroll
  for (int j = 1; j < kLanes; ++j)
    if (costr[j] < amin) { amin = costr[j]; aidx = j; }

  float Mf[kLanes];
#pragma unroll
  for (int j = 0; j < kLanes; ++j) Mf[j] = (float)Mi[j];
  if (msum > 1) {
    Mf[0] = 0.0f;
    Mf[aidx] = 1.0f;
  }

  const float mfsum = Mf[0] + Mf[1] + Mf[2] + Mf[3];
  const int cls_t = (mfsum > 0.0f) ? 1 : 0;

  // ---- focal classification term ----
  const float mx = fmaxf(p0, p1);
  const float e0 = expf(p0 - mx), e1 = expf(p1 - mx);
  const float inv = 1.0f / (e0 + e1);
  const float q = (cls_t ? e1 : e0) * inv + 1e-8f;
  const float omq = 1.0f - q;
  const float focal = -0.25f * omq * omq * logf(q);

  // ---- reg (smooth L1) + iou terms for matched pairs ----
  const float pred_start = fminf(fmaxf(rintf(p2 * 71.0f), 0.0f), 71.0f);
  const float py0 = p2 * 71.0f, py1 = p3 * 799.0f, py2t = p4 * 180.0f, py3 = p5 * 71.0f;
  float regc = 0.0f, iouc = 0.0f;
#pragma unroll
  for (int j = 0; j < kLanes; ++j) {
    if (Mf[j] > 0.0f) {
      float t30 = s_hdr[j][2] * 71.0f;
      float t31 = s_hdr[j][3];
      float t32 = s_hdr[j][4] * 180.0f;
      float tstart = rintf(s_hdr[j][2] * 71.0f);
      float tlp = s_hdr[j][5] - (pred_start - tstart);
      regc += smoothL1(py0 - t30) + smoothL1(py1 - t31) + smoothL1(py2t - t32)
            + smoothL1(py3 - tlp);
      iouc += 1.0f - iou[j];
    }
  }

  // ---- block sum reduce (4 values) ----
  float v0 = mfsum, v1 = focal, v2 = regc, v3 = iouc;
#pragma unroll
  for (int off = 32; off; off >>= 1) {
    v0 += __shfl_down(v0, off, 64);
    v1 += __shfl_down(v1, off, 64);
    v2 += __shfl_down(v2, off, 64);
    v3 += __shfl_down(v3, off, 64);
  }
  __syncthreads();   // s_sc reuse hazard
  if (lane == 0) {
    s_sc[wav][0] = v0; s_sc[wav][1] = v1; s_sc[wav][2] = v2; s_sc[wav][3] = v3;
  }
  __syncthreads();

  if (tid == 0) {
    float nm      = s_sc[0][0] + s_sc[1][0] + s_sc[2][0];
    float cls_sum = s_sc[0][1] + s_sc[1][1] + s_sc[2][1];
    float reg_sum = s_sc[0][2] + s_sc[1][2] + s_sc[2][2];
    float iou_sum = s_sc[0][3] + s_sc[1][3] + s_sc[2][3];

    float cls_term = cls_sum / (has_t ? (float)num_t : 1.0f);
    float reg_term = has_t ? reg_sum / fmaxf(nm * 4.0f, 1.0f) : 0.0f;
    float iou_term = has_t ? iou_sum / fmaxf(nm, 1.0f) : 0.0f;

    float sample = 2.0f * cls_term + 0.2f * reg_term + 2.0f * iou_term;
    atomicAdd(out, sample * (1.0f / (float)(kBatch * kStages)));
  }
}

extern "C" void kernel_launch(void* const* d_in, const int* in_sizes, int n_in,
                              void* d_out, int out_size, void* d_ws, size_t ws_size,
                              hipStream_t stream) {
  const float* pred = (const float*)d_in[0];   // (3,512,192,78) f32
  const float* tgt  = (const float*)d_in[1];   // (512,4,78) f32
  const float* seg  = (const float*)d_in[2];   // scalar f32
  float* out = (float*)d_out;                  // scalar f32

  clr_init<<<1, 1, 0, stream>>>(seg, out);
  clr_loss_kernel<<<kStages * kBatch, 192, 0, stream>>>(pred, tgt, out);
}